// Round 16
// baseline (289.142 us; speedup 1.0000x reference)
//
#include <hip/hip_runtime.h>
#include <hip/hip_fp16.h>

#define DMODEL 192
#define DINNER 384
#define NPOS   4096   // B*H*W = 4*32*32
#define SEQL   1024   // H*W
#define DSTATE 16
#define DTRANK 12

__device__ __forceinline__ float silu_f(float v) { return v * (1.f / (1.f + __expf(-v))); }
__device__ __forceinline__ int swiz(int s) { return ((s & 31) << 5) | (s >> 5); }

// ---------------------------------------------------------------------------
// K1: xz = x @ W_in. Wave-uniform x reads (scalar-load path), no LDS.
//     1536 blocks x 256 thr. (round-15 verified)
// ---------------------------------------------------------------------------
__global__ void k1_inproj(const float* __restrict__ x, const float* __restrict__ W_in,
                          float* __restrict__ x_val, float* __restrict__ gz) {
    const int t = threadIdx.x;
    const int bi = blockIdx.x;
    const int colg = bi % 3;
    const int pos0 = (bi / 3) << 3;
    const int col = colg * 256 + t;

    const float* xr = x + pos0 * DMODEL;

    float acc[8] = {0,0,0,0,0,0,0,0};
    for (int c = 0; c < DMODEL; c += 4) {
        float w0 = W_in[(c + 0) * 768 + col];
        float w1 = W_in[(c + 1) * 768 + col];
        float w2 = W_in[(c + 2) * 768 + col];
        float w3 = W_in[(c + 3) * 768 + col];
#pragma unroll
        for (int g = 0; g < 8; ++g) {
            const float4 xv = *(const float4*)&xr[g * DMODEL + c];
            acc[g] += xv.x * w0 + xv.y * w1 + xv.z * w2 + xv.w * w3;
        }
    }
    if (col < DINNER) {
#pragma unroll
        for (int g = 0; g < 8; ++g) x_val[(pos0 + g) * DINNER + col] = acc[g];
    } else {
#pragma unroll
        for (int g = 0; g < 8; ++g) gz[(pos0 + g) * DINNER + (col - DINNER)] = silu_f(acc[g]);
    }
}

// ---------------------------------------------------------------------------
// K2: conv3x3+silu -> (dt, du=dt*u, y_init=4*D*u, xd). No u array (dead).
//     4096 blocks x 384 thr. y_acc SEPARATE from x_val (halo-race invariant).
// ---------------------------------------------------------------------------
__global__ void k2_conv_dt(const float* __restrict__ x_val,
                           const float* __restrict__ conv_w, const float* __restrict__ conv_b,
                           const float* __restrict__ W_x, const float* __restrict__ W_dt,
                           const float* __restrict__ b_dt, const float* __restrict__ Dp,
                           float* __restrict__ xd_out, float* __restrict__ dt32,
                           float* __restrict__ du_out, float* __restrict__ y_acc) {
    __shared__ float us[DINNER];
    __shared__ float part[8 * 44];
    __shared__ float xdl[44];
    const int t = threadIdx.x;
    const int pos = blockIdx.x;
    const int b = pos >> 10, hw = pos & 1023, h = hw >> 5, w = hw & 31;

    float acc = conv_b[t];
#pragma unroll
    for (int i = 0; i < 3; ++i) {
        int hh = h + i - 1;
        if (hh < 0 || hh > 31) continue;
#pragma unroll
        for (int j = 0; j < 3; ++j) {
            int ww = w + j - 1;
            if (ww < 0 || ww > 31) continue;
            acc += x_val[((b * 32 + hh) * 32 + ww) * DINNER + t] * conv_w[t * 9 + i * 3 + j];
        }
    }
    float uv = silu_f(acc);
    us[t] = uv;
    __syncthreads();

    if (t < 352) {
        int o = t % 44, p = t / 44;
        float s = 0.f;
        int j0 = p * 48;
        for (int j = j0; j < j0 + 48; ++j) s += us[j] * W_x[j * 44 + o];
        part[p * 44 + o] = s;
    }
    __syncthreads();
    if (t < 44) {
        float s = 0.f;
#pragma unroll
        for (int p = 0; p < 8; ++p) s += part[p * 44 + t];
        xd_out[pos * 48 + t] = s;
        xdl[t] = s;
    }
    __syncthreads();

    float raw = b_dt[t];
#pragma unroll
    for (int r = 0; r < DTRANK; ++r) raw += xdl[r] * W_dt[r * DINNER + t];
    float dtv = fmaxf(raw, 0.f) + log1pf(__expf(-fabsf(raw)));
    dt32[pos * DINNER + t]   = dtv;
    du_out[pos * DINNER + t] = dtv * uv;
    y_acc[pos * DINNER + t]  = 4.f * Dp[t] * uv;
}

// ---------------------------------------------------------------------------
// K2pA/B: prefix sums of dt along the two scan orders (row-major P0 and
//         transposed P2), 2-pass chunked scan. 64 blocks x 384 thr each.
//         All-positive sums -> reassociation numerically trivial.
// ---------------------------------------------------------------------------
__global__ void k2pA(const float* __restrict__ dt32, float* __restrict__ tot) {
    const int t = threadIdx.x;               // d
    const int bi = blockIdx.x;               // 64 = o(2) * b(4) * c(8)
    const int c = bi & 7, b = (bi >> 3) & 3, o = bi >> 5;
    const float* base = dt32 + b * SEQL * DINNER + t;
    float s = 0.f;
    for (int i = 0; i < 128; ++i) {
        int l = c * 128 + i;
        int pos = o ? swiz(l) : l;
        s += base[pos * DINNER];
    }
    tot[((o * 4 + b) * 8 + c) * DINNER + t] = s;
}

__global__ void k2pB(const float* __restrict__ dt32, const float* __restrict__ tot,
                     float* __restrict__ P0, float* __restrict__ P2) {
    const int t = threadIdx.x;
    const int bi = blockIdx.x;
    const int c = bi & 7, b = (bi >> 3) & 3, o = bi >> 5;
    float run = 0.f;
    for (int cc = 0; cc < 8; ++cc)
        if (cc < c) run += tot[((o * 4 + b) * 8 + cc) * DINNER + t];
    const float* base = dt32 + b * SEQL * DINNER + t;
    float* P = (o ? P2 : P0) + b * SEQL * DINNER + t;
    for (int i = 0; i < 128; ++i) {
        int l = c * 128 + i;
        int pos = o ? swiz(l) : l;
        run += base[pos * DINNER];
        P[l * DINNER] = run;
    }
}

// ---------------------------------------------------------------------------
// K3: scan with PRECOMPUTED cumdt — decay = exp(A * cumdt(l)) is independent
//     per step (no serial cum chain). Only serial dep: 1 FMA/step S chain.
//     Ballot early exit on last step of chunk. 384 blocks x 256 thr.
// ---------------------------------------------------------------------------
__global__ void k3_scan(const float* __restrict__ du, const float* __restrict__ xd,
                        const float* __restrict__ P0, const float* __restrict__ P2,
                        const float* __restrict__ A_log, float* __restrict__ y_acc) {
    const int t = threadIdx.x;
    const int n = t & 15, dl = t >> 4;
    const int bi = blockIdx.x;
    const int chunk = bi % 24;
    const int b = (bi / 24) % 4;
    const int dir = bi / 96;
    const int d = chunk * 16 + dl;

    const float A = -__expf(A_log[d * DSTATE + n]);
    const int fwd = !(dir & 1);

    const float* Pb  = ((dir & 2) ? P2 : P0) + b * SEQL * DINNER + d;
    const float  T   = Pb[(SEQL - 1) * DINNER];
    const float* dub = du + b * SEQL * DINNER + d;
    const float* xb  = xd + b * SEQL * 48;
    float* yb = y_acc + b * SEQL * DINNER;

    float S = 0.f;
    for (int l0 = 0; l0 < SEQL; l0 += 8) {
        float cumv[8], duv[8], Bv[8], Cv[8];
        int pk[8];
#pragma unroll
        for (int k = 0; k < 8; ++k) {
            int l = l0 + k;
            int s = fwd ? l : (SEQL - 1 - l);
            int pos = (dir & 2) ? swiz(s) : s;
            pk[k] = pos;
            cumv[k] = fwd ? Pb[l * DINNER]
                          : (l == SEQL - 1 ? T : T - Pb[(SEQL - 2 - l) * DINNER]);
            duv[k] = dub[pos * DINNER];
            Bv[k]  = xb[pos * 48 + DTRANK + n];
            Cv[k]  = xb[pos * 48 + DTRANK + DSTATE + n];
        }
        float decay[8], rc[8], c[8];
#pragma unroll
        for (int k = 0; k < 8; ++k) decay[k] = __expf(A * cumv[k]);
#pragma unroll
        for (int k = 0; k < 8; ++k) rc[k] = __builtin_amdgcn_rcpf(decay[k] + 1e-12f);
#pragma unroll
        for (int k = 0; k < 8; ++k) {
            S += (duv[k] * Bv[k]) * rc[k];
            c[k] = decay[k] * S * Cv[k];
        }
#pragma unroll
        for (int off = 1; off <= 8; off <<= 1) {
#pragma unroll
            for (int k = 0; k < 8; ++k) c[k] += __shfl_xor(c[k], off);
        }
        if (n == 0) {
#pragma unroll
            for (int k = 0; k < 8; ++k) atomicAdd(&yb[pk[k] * DINNER + d], c[k]);
        }
        if (__ballot(A * cumv[7] > -110.f) == 0ull) break;  // monotone -> rest exact 0
    }
}

// ---------------------------------------------------------------------------
// K4: LayerNorm + gate + out-proj. 512 blocks x 384 thr, 8 pos/block.
//     (round-14 verified)
// ---------------------------------------------------------------------------
__global__ void k4_out(const float* __restrict__ y_acc, const float* __restrict__ gz,
                       const float* __restrict__ gamma, const float* __restrict__ beta,
                       const float* __restrict__ W_out, float* __restrict__ out) {
    __shared__ float g_s[8 * DINNER];
    __shared__ float red[12];
    const int t = threadIdx.x;
    const int half = t / 192, tc = t % 192;
    const int lane = t & 63, wv = t >> 6;
    const int pos0 = blockIdx.x << 3;

    const float g0c = gamma[tc], g1c = gamma[tc + 192];
    const float b0c = beta[tc],  b1c = beta[tc + 192];

    for (int it = 0; it < 4; ++it) {
        int p = it * 2 + half;
        int pos = pos0 + p;
        float y0 = y_acc[pos * DINNER + tc];
        float y1 = y_acc[pos * DINNER + tc + 192];

        float s = y0 + y1;
#pragma unroll
        for (int off = 32; off > 0; off >>= 1) s += __shfl_xor(s, off);
        if (lane == 0) red[wv] = s;
        __syncthreads();
        float mu = (red[half * 3] + red[half * 3 + 1] + red[half * 3 + 2]) * (1.f / 384.f);

        float d0 = y0 - mu, d1 = y1 - mu;
        float sq = d0 * d0 + d1 * d1;
#pragma unroll
        for (int off = 32; off > 0; off >>= 1) sq += __shfl_xor(sq, off);
        if (lane == 0) red[6 + wv] = sq;
        __syncthreads();
        float var = (red[6 + half * 3] + red[6 + half * 3 + 1] + red[6 + half * 3 + 2]) * (1.f / 384.f);
        float inv = rsqrtf(var + 1e-5f);

        g_s[p * DINNER + tc]       = (d0 * inv * g0c + b0c) * gz[pos * DINNER + tc];
        g_s[p * DINNER + tc + 192] = (d1 * inv * g1c + b1c) * gz[pos * DINNER + tc + 192];
    }
    __syncthreads();

    float acc[4] = {0.f, 0.f, 0.f, 0.f};
    const int pbase = half * 4;
    for (int dd = 0; dd < DINNER; dd += 4) {
        float w0 = W_out[(dd + 0) * DMODEL + tc];
        float w1 = W_out[(dd + 1) * DMODEL + tc];
        float w2 = W_out[(dd + 2) * DMODEL + tc];
        float w3 = W_out[(dd + 3) * DMODEL + tc];
#pragma unroll
        for (int i = 0; i < 4; ++i) {
            const float4 g = *(const float4*)&g_s[(pbase + i) * DINNER + dd];
            acc[i] += g.x * w0 + g.y * w1 + g.z * w2 + g.w * w3;
        }
    }
#pragma unroll
    for (int i = 0; i < 4; ++i) out[(pos0 + pbase + i) * DMODEL + tc] = acc[i];
}

// ---------------------------------------------------------------------------
extern "C" void kernel_launch(void* const* d_in, const int* in_sizes, int n_in,
                              void* d_out, int out_size, void* d_ws, size_t ws_size,
                              hipStream_t stream) {
    (void)in_sizes; (void)n_in; (void)out_size; (void)ws_size;
    const float* x      = (const float*)d_in[0];
    const float* W_in   = (const float*)d_in[1];
    const float* conv_w = (const float*)d_in[2];
    const float* conv_b = (const float*)d_in[3];
    const float* W_x    = (const float*)d_in[4];
    const float* W_dt   = (const float*)d_in[5];
    const float* b_dt   = (const float*)d_in[6];
    const float* A_log  = (const float*)d_in[7];
    const float* Dp     = (const float*)d_in[8];
    const float* W_out  = (const float*)d_in[9];
    const float* gamma  = (const float*)d_in[10];
    const float* beta   = (const float*)d_in[11];

    // ws layout (~43 MB; ws_size ~256 MiB per fill counter evidence):
    char* base = (char*)d_ws;
    float* x_val = (float*)(base + 0);          // 6 MB
    float* xd    = (float*)(base + 6291456);    // 0.75 MB
    float* dt32  = (float*)(base + 7077888);    // 6 MB
    float* du    = (float*)(base + 13369344);   // 6 MB
    float* gz    = (float*)(base + 19660800);   // 6 MB
    float* y_acc = (float*)(base + 25952256);   // 6 MB  (SEPARATE from x_val)
    float* P0    = (float*)(base + 32243712);   // 6 MB
    float* P2    = (float*)(base + 38535168);   // 6 MB
    float* tot   = (float*)(base + 44826624);   // 96 KB

    hipLaunchKernelGGL(k1_inproj, dim3(NPOS / 8 * 3), dim3(256), 0, stream, x, W_in, x_val, gz);
    hipLaunchKernelGGL(k2_conv_dt, dim3(NPOS), dim3(384), 0, stream,
                       x_val, conv_w, conv_b, W_x, W_dt, b_dt, Dp, xd, dt32, du, y_acc);
    hipLaunchKernelGGL(k2pA, dim3(64), dim3(384), 0, stream, dt32, tot);
    hipLaunchKernelGGL(k2pB, dim3(64), dim3(384), 0, stream, dt32, tot, P0, P2);
    hipLaunchKernelGGL(k3_scan, dim3(384), dim3(256), 0, stream,
                       du, xd, P0, P2, A_log, y_acc);
    hipLaunchKernelGGL(k4_out, dim3(NPOS / 8), dim3(384), 0, stream,
                       y_acc, gz, gamma, beta, W_out, (float*)d_out);
}

// Round 17
// 213.001 us; speedup vs baseline: 1.3575x; 1.3575x over previous
//
#include <hip/hip_runtime.h>
#include <hip/hip_fp16.h>

#define DMODEL 192
#define DINNER 384
#define NPOS   4096   // B*H*W = 4*32*32
#define SEQL   1024   // H*W
#define DSTATE 16
#define DTRANK 12

__device__ __forceinline__ float silu_f(float v) { return v * (1.f / (1.f + __expf(-v))); }

__device__ __forceinline__ int scan_pos(int dir, int l) {
    int s = (dir & 1) ? (SEQL - 1 - l) : l;
    return (dir & 2) ? (((s & 31) << 5) | (s >> 5)) : s;
}

// ---------------------------------------------------------------------------
// K1: xz = x @ W_in. Wave-uniform x reads (scalar-load path), no LDS.
//     1536 blocks x 256 thr. (round-15 verified)
// ---------------------------------------------------------------------------
__global__ void k1_inproj(const float* __restrict__ x, const float* __restrict__ W_in,
                          float* __restrict__ x_val, float* __restrict__ gz) {
    const int t = threadIdx.x;
    const int bi = blockIdx.x;
    const int colg = bi % 3;
    const int pos0 = (bi / 3) << 3;
    const int col = colg * 256 + t;

    const float* xr = x + pos0 * DMODEL;

    float acc[8] = {0,0,0,0,0,0,0,0};
    for (int c = 0; c < DMODEL; c += 4) {
        float w0 = W_in[(c + 0) * 768 + col];
        float w1 = W_in[(c + 1) * 768 + col];
        float w2 = W_in[(c + 2) * 768 + col];
        float w3 = W_in[(c + 3) * 768 + col];
#pragma unroll
        for (int g = 0; g < 8; ++g) {
            const float4 xv = *(const float4*)&xr[g * DMODEL + c];
            acc[g] += xv.x * w0 + xv.y * w1 + xv.z * w2 + xv.w * w3;
        }
    }
    if (col < DINNER) {
#pragma unroll
        for (int g = 0; g < 8; ++g) x_val[(pos0 + g) * DINNER + col] = acc[g];
    } else {
#pragma unroll
        for (int g = 0; g < 8; ++g) gz[(pos0 + g) * DINNER + (col - DINNER)] = silu_f(acc[g]);
    }
}

// ---------------------------------------------------------------------------
// K2: depthwise conv3x3 + bias + silu -> u (fp16) ; xd = u @ W_x (44 cols) ;
//     dt = softplus(b_dt + xd[:12] @ W_dt) ; y_acc init = 4*D*u.
//     y_acc SEPARATE from x_val (halo-race invariant).
// ---------------------------------------------------------------------------
__global__ void k2_conv_dt(const float* __restrict__ x_val,
                           const float* __restrict__ conv_w, const float* __restrict__ conv_b,
                           const float* __restrict__ W_x, const float* __restrict__ W_dt,
                           const float* __restrict__ b_dt, const float* __restrict__ Dp,
                           __half* __restrict__ u_out, float* __restrict__ xd_out,
                           float* __restrict__ dt32, float* __restrict__ y_acc) {
    __shared__ float us[DINNER];
    __shared__ float part[8 * 44];
    __shared__ float xdl[44];
    const int t = threadIdx.x;
    const int pos = blockIdx.x;
    const int b = pos >> 10, hw = pos & 1023, h = hw >> 5, w = hw & 31;

    float acc = conv_b[t];
#pragma unroll
    for (int i = 0; i < 3; ++i) {
        int hh = h + i - 1;
        if (hh < 0 || hh > 31) continue;
#pragma unroll
        for (int j = 0; j < 3; ++j) {
            int ww = w + j - 1;
            if (ww < 0 || ww > 31) continue;
            acc += x_val[((b * 32 + hh) * 32 + ww) * DINNER + t] * conv_w[t * 9 + i * 3 + j];
        }
    }
    float uv = silu_f(acc);
    us[t] = uv;
    u_out[pos * DINNER + t] = __float2half(uv);
    __syncthreads();

    if (t < 352) {
        int o = t % 44, p = t / 44;
        float s = 0.f;
        int j0 = p * 48;
        for (int j = j0; j < j0 + 48; ++j) s += us[j] * W_x[j * 44 + o];
        part[p * 44 + o] = s;
    }
    __syncthreads();
    if (t < 44) {
        float s = 0.f;
#pragma unroll
        for (int p = 0; p < 8; ++p) s += part[p * 44 + t];
        xd_out[pos * 48 + t] = s;
        xdl[t] = s;
    }
    __syncthreads();

    float raw = b_dt[t];
#pragma unroll
    for (int r = 0; r < DTRANK; ++r) raw += xdl[r] * W_dt[r * DINNER + t];
    dt32[pos * DINNER + t] = fmaxf(raw, 0.f) + log1pf(__expf(-fabsf(raw)));

    y_acc[pos * DINNER + t] = 4.f * Dp[t] * uv;
}

// ---------------------------------------------------------------------------
// K3: batched-phase scan with 2-buffer software-pipelined prefetch.
//     __launch_bounds__(256, 1): grid is only 384 blocks (~1.5 waves/SIMD),
//     so free the register budget — without this the compiler caps at ~52
//     VGPRs (8-wave heuristic) and re-serializes the prefetch (rounds 14-16).
//     Arithmetic & reduction order identical to round 15. 384 blocks x 256.
// ---------------------------------------------------------------------------
__device__ __forceinline__ void k3_load(const float* __restrict__ dtb,
                                        const float* __restrict__ xb,
                                        const __half* __restrict__ ub,
                                        int dir, int l0, int d, int n,
                                        float* dtv, float* Bv, float* Cv, float* uv, int* pk) {
#pragma unroll
    for (int k = 0; k < 8; ++k) {
        int pos = scan_pos(dir, l0 + k);
        pk[k]  = pos;
        dtv[k] = dtb[pos * DINNER + d];
        Bv[k]  = xb[pos * 48 + DTRANK + n];
        Cv[k]  = xb[pos * 48 + DTRANK + DSTATE + n];
        uv[k]  = __half2float(ub[pos * DINNER + d]);
    }
}

__device__ __forceinline__ bool k3_compute(float A, float& cum, float& S,
                                           const float* dtv, const float* Bv,
                                           const float* Cv, const float* uv, const int* pk,
                                           float* __restrict__ yb, int d, int n) {
    float decay[8];
#pragma unroll
    for (int k = 0; k < 8; ++k) { cum += dtv[k] * A; decay[k] = __expf(cum); }
    float rc[8];
#pragma unroll
    for (int k = 0; k < 8; ++k) rc[k] = __builtin_amdgcn_rcpf(decay[k] + 1e-12f);
    float c[8];
#pragma unroll
    for (int k = 0; k < 8; ++k) {
        S += (dtv[k] * Bv[k] * uv[k]) * rc[k];
        c[k] = decay[k] * S * Cv[k];
    }
#pragma unroll
    for (int off = 1; off <= 8; off <<= 1) {
#pragma unroll
        for (int k = 0; k < 8; ++k) c[k] += __shfl_xor(c[k], off);
    }
    if (n == 0) {
#pragma unroll
        for (int k = 0; k < 8; ++k) atomicAdd(&yb[pk[k] * DINNER + d], c[k]);
    }
    return __ballot(cum > -110.f) != 0ull;       // alive?
}

__global__ void __launch_bounds__(256, 1)
k3_early(const __half* __restrict__ u, const float* __restrict__ xd,
         const float* __restrict__ dt32, const float* __restrict__ A_log,
         float* __restrict__ y_acc) {
    const int t = threadIdx.x;
    const int n = t & 15, dl = t >> 4;
    const int bi = blockIdx.x;
    const int chunk = bi % 24;
    const int b = (bi / 24) % 4;
    const int dir = bi / 96;
    const int d = chunk * 16 + dl;

    const float A = -__expf(A_log[d * DSTATE + n]);

    const __half* ub  = u    + b * SEQL * DINNER;
    const float* xb   = xd   + b * SEQL * 48;
    const float* dtb  = dt32 + b * SEQL * DINNER;
    float* yb = y_acc + b * SEQL * DINNER;

    float dtvA[8], BvA[8], CvA[8], uvA[8]; int pkA[8];
    float dtvB[8], BvB[8], CvB[8], uvB[8]; int pkB[8];

    float cum = 0.f, S = 0.f;
    k3_load(dtb, xb, ub, dir, 0, d, n, dtvA, BvA, CvA, uvA, pkA);
    for (int l0 = 0; l0 < SEQL; l0 += 16) {
        // prefetch chunk l0+8 (always in range: l0 <= 1008)
        k3_load(dtb, xb, ub, dir, l0 + 8, d, n, dtvB, BvB, CvB, uvB, pkB);
        if (!k3_compute(A, cum, S, dtvA, BvA, CvA, uvA, pkA, yb, d, n)) break;
        // prefetch chunk l0+16 (redundant reload at the tail; harmless)
        int ln = (l0 + 16 < SEQL) ? (l0 + 16) : (l0 + 8);
        k3_load(dtb, xb, ub, dir, ln, d, n, dtvA, BvA, CvA, uvA, pkA);
        if (!k3_compute(A, cum, S, dtvB, BvB, CvB, uvB, pkB, yb, d, n)) break;
    }
}

// ---------------------------------------------------------------------------
// K4: LayerNorm + gate + out-proj. 512 blocks x 384 thr, 8 pos/block.
//     (round-14 verified)
// ---------------------------------------------------------------------------
__global__ void k4_out(const float* __restrict__ y_acc, const float* __restrict__ gz,
                       const float* __restrict__ gamma, const float* __restrict__ beta,
                       const float* __restrict__ W_out, float* __restrict__ out) {
    __shared__ float g_s[8 * DINNER];
    __shared__ float red[12];
    const int t = threadIdx.x;
    const int half = t / 192, tc = t % 192;
    const int lane = t & 63, wv = t >> 6;
    const int pos0 = blockIdx.x << 3;

    const float g0c = gamma[tc], g1c = gamma[tc + 192];
    const float b0c = beta[tc],  b1c = beta[tc + 192];

    for (int it = 0; it < 4; ++it) {
        int p = it * 2 + half;
        int pos = pos0 + p;
        float y0 = y_acc[pos * DINNER + tc];
        float y1 = y_acc[pos * DINNER + tc + 192];

        float s = y0 + y1;
#pragma unroll
        for (int off = 32; off > 0; off >>= 1) s += __shfl_xor(s, off);
        if (lane == 0) red[wv] = s;
        __syncthreads();
        float mu = (red[half * 3] + red[half * 3 + 1] + red[half * 3 + 2]) * (1.f / 384.f);

        float d0 = y0 - mu, d1 = y1 - mu;
        float sq = d0 * d0 + d1 * d1;
#pragma unroll
        for (int off = 32; off > 0; off >>= 1) sq += __shfl_xor(sq, off);
        if (lane == 0) red[6 + wv] = sq;
        __syncthreads();
        float var = (red[6 + half * 3] + red[6 + half * 3 + 1] + red[6 + half * 3 + 2]) * (1.f / 384.f);
        float inv = rsqrtf(var + 1e-5f);

        g_s[p * DINNER + tc]       = (d0 * inv * g0c + b0c) * gz[pos * DINNER + tc];
        g_s[p * DINNER + tc + 192] = (d1 * inv * g1c + b1c) * gz[pos * DINNER + tc + 192];
    }
    __syncthreads();

    float acc[4] = {0.f, 0.f, 0.f, 0.f};
    const int pbase = half * 4;
    for (int dd = 0; dd < DINNER; dd += 4) {
        float w0 = W_out[(dd + 0) * DMODEL + tc];
        float w1 = W_out[(dd + 1) * DMODEL + tc];
        float w2 = W_out[(dd + 2) * DMODEL + tc];
        float w3 = W_out[(dd + 3) * DMODEL + tc];
#pragma unroll
        for (int i = 0; i < 4; ++i) {
            const float4 g = *(const float4*)&g_s[(pbase + i) * DINNER + dd];
            acc[i] += g.x * w0 + g.y * w1 + g.z * w2 + g.w * w3;
        }
    }
#pragma unroll
    for (int i = 0; i < 4; ++i) out[(pos0 + pbase + i) * DMODEL + tc] = acc[i];
}

// ---------------------------------------------------------------------------
extern "C" void kernel_launch(void* const* d_in, const int* in_sizes, int n_in,
                              void* d_out, int out_size, void* d_ws, size_t ws_size,
                              hipStream_t stream) {
    (void)in_sizes; (void)n_in; (void)out_size; (void)ws_size;
    const float* x      = (const float*)d_in[0];
    const float* W_in   = (const float*)d_in[1];
    const float* conv_w = (const float*)d_in[2];
    const float* conv_b = (const float*)d_in[3];
    const float* W_x    = (const float*)d_in[4];
    const float* W_dt   = (const float*)d_in[5];
    const float* b_dt   = (const float*)d_in[6];
    const float* A_log  = (const float*)d_in[7];
    const float* Dp     = (const float*)d_in[8];
    const float* W_out  = (const float*)d_in[9];
    const float* gamma  = (const float*)d_in[10];
    const float* beta   = (const float*)d_in[11];

    // ws layout (27.75 MB, verified):
    //  x_val fp32 : 6 MB    @ 0
    //  u     fp16 : 3 MB    @ 6291456
    //  xd    fp32 : 0.75 MB @ 9437184
    //  dt32  fp32 : 6 MB    @ 10223616
    //  gz    fp32 : 6 MB    @ 16515072
    //  y_acc fp32 : 6 MB    @ 22806528   (SEPARATE from x_val: no halo race)
    char* base = (char*)d_ws;
    float*  x_val = (float*)base;
    __half* u     = (__half*)(base + 6291456);
    float*  xd    = (float*)(base + 9437184);
    float*  dt32  = (float*)(base + 10223616);
    float*  gz    = (float*)(base + 16515072);
    float*  y_acc = (float*)(base + 22806528);

    hipLaunchKernelGGL(k1_inproj, dim3(NPOS / 8 * 3), dim3(256), 0, stream, x, W_in, x_val, gz);
    hipLaunchKernelGGL(k2_conv_dt, dim3(NPOS), dim3(384), 0, stream,
                       x_val, conv_w, conv_b, W_x, W_dt, b_dt, Dp, u, xd, dt32, y_acc);
    hipLaunchKernelGGL(k3_early, dim3(384), dim3(256), 0, stream,
                       u, xd, dt32, A_log, y_acc);
    hipLaunchKernelGGL(k4_out, dim3(NPOS / 8), dim3(384), 0, stream,
                       y_acc, gz, gamma, beta, W_out, (float*)d_out);
}